// Round 11
// baseline (158.876 us; speedup 1.0000x reference)
//
#include <hip/hip_runtime.h>
#include <stdint.h>
#include <stddef.h>

#define BB 4
#define NN 4096
#define DD 128

typedef _Float16 f16;
typedef _Float16 f16x8 __attribute__((ext_vector_type(8)));
typedef float f32x4 __attribute__((ext_vector_type(4)));
typedef float f32x2 __attribute__((ext_vector_type(2)));

__device__ __forceinline__ void gl16(const f16* g, f16* l) {
  __builtin_amdgcn_global_load_lds(
      (const __attribute__((address_space(1))) unsigned int*)g,
      (__attribute__((address_space(3))) unsigned int*)l,
      16, 0, 0);
}

__device__ __forceinline__ float fast_sqrt(float x) {
  float r;
  asm("v_sqrt_f32 %0, %1" : "=v"(r) : "v"(x));
  return r;
}

// ---- prep: f16 hi/lo split, numpy-exact row norms, input copies ----------
__global__ __launch_bounds__(256) void prep_kernel(
    const float* __restrict__ x1, const float* __restrict__ x2,
    f16* __restrict__ x1h, f16* __restrict__ x1l,
    f16* __restrict__ x2h, f16* __restrict__ x2l,
    float* __restrict__ sq1, float* __restrict__ sq2,
    float* __restrict__ out)
{
  int gtid = blockIdx.x * blockDim.x + threadIdx.x;
  int gwave = gtid >> 6;
  int lane = gtid & 63;
  int sub = lane >> 3;
  int j = lane & 7;
  int row = gwave * 8 + sub;
  const float* src; f16* dh; f16* dl; float* sq; float* cpy; int r;
  if (row < BB * NN) {
    r = row; src = x1; dh = x1h; dl = x1l; sq = sq1; cpy = out;
  } else {
    r = row - BB * NN; src = x2; dh = x2h; dl = x2l; sq = sq2;
    cpy = out + (size_t)BB * NN * DD;
  }
  const float* p = src + (size_t)r * DD;
  float acc = 0.0f;
  #pragma unroll
  for (int i = 0; i < DD / 8; ++i) {
    int c = j + i * 8;
    float v = p[c];
    float s = v * v;
    acc = (i == 0) ? s : (acc + s);
    f16 h = (f16)v;
    f16 l = (f16)(v - (float)h);
    dh[(size_t)r * DD + c] = h;
    dl[(size_t)r * DD + c] = l;
    cpy[(size_t)r * DD + c] = v;
  }
  acc = acc + __shfl_xor(acc, 1);
  acc = acc + __shfl_xor(acc, 2);
  acc = acc + __shfl_xor(acc, 4);
  if (j == 0) sq[r] = acc;
}

// ---- main: 64x64 tile, 4 waves (2x2, each 32x32), BK=32, split-f16,
//      single-buffer 2-barrier loop, 5 blocks/CU (20 waves), NT stores ----
__global__ __launch_bounds__(256, 5) void cdist_kernel(
    const f16* __restrict__ x1h, const f16* __restrict__ x1l,
    const f16* __restrict__ x2h, const f16* __restrict__ x2l,
    const float* __restrict__ sq1, const float* __restrict__ sq2,
    float* __restrict__ corr,
    f32x2* __restrict__ p21, f32x2* __restrict__ p12)
{
  __shared__ f16 Ah[64 * 32];
  __shared__ f16 Al[64 * 32];
  __shared__ f16 Bh[64 * 32];
  __shared__ f16 Bl[64 * 32];
  __shared__ float s1s[64];
  __shared__ float s2s[64];

  const int b = blockIdx.z;
  // bijective XCD swizzle over 4096 xy tiles (4096 % 8 == 0)
  int lin = blockIdx.y * 64 + blockIdx.x;
  lin = (lin & 7) * 512 + (lin >> 3);
  const int sbx = lin & 63;    // n1 tile
  const int sby = lin >> 6;    // n2 tile
  const int bn1 = sbx * 64;
  const int bn2 = sby * 64;

  const int t = threadIdx.x;
  const int wa = t >> 6;
  const int lane = t & 63;
  const int w1 = wa & 1;     // n1 32-half
  const int w2 = wa >> 1;    // n2 32-half
  const int lr = lane & 15;
  const int lg = lane >> 4;

  const f16* gAh = x1h + (size_t)b * NN * DD;
  const f16* gAl = x1l + (size_t)b * NN * DD;
  const f16* gBh = x2h + (size_t)b * NN * DD;
  const f16* gBl = x2l + (size_t)b * NN * DD;

  if (t < 64) s1s[t] = sq1[(size_t)b * NN + bn1 + t];
  else if (t < 128) s2s[t - 64] = sq2[(size_t)b * NN + bn2 + (t - 64)];

  // staging: each wave stages 16 rows (1KB seg) of each of the 4 arrays.
  // swizzled global source, linear LDS dest (rule #21).
  const int srow = wa * 16 + (lane >> 2);
  const int kc8 = ((lane & 3) ^ (srow & 3) ^ ((srow >> 2) & 3)) * 8;
  const int aoff = (bn1 + srow) * DD + kc8;
  const int boff = (bn2 + srow) * DD + kc8;
  const int loff = wa * 512;   // wave-uniform LDS base (f16 elems)
#define STAGE(k0) do { \
    gl16(gAh + aoff + (k0), &Ah[loff]); \
    gl16(gAl + aoff + (k0), &Al[loff]); \
    gl16(gBh + boff + (k0), &Bh[loff]); \
    gl16(gBl + boff + (k0), &Bl[loff]); } while (0)

  f32x4 acc[2][2];
  #pragma unroll
  for (int m = 0; m < 2; ++m)
    #pragma unroll
    for (int n = 0; n < 2; ++n)
      #pragma unroll
      for (int q = 0; q < 4; ++q) acc[m][n][q] = 0.0f;

  STAGE(0);

  // swizzled read offset (frag row % 16 == lr; m*16, w*32 preserve mod-4 bits)
  const int lgx8 = (lg ^ (lr & 3) ^ ((lr >> 2) & 3)) * 8;
  const int offA0 = (w1 * 32 + lr) * 32 + lgx8;
  const int offB0 = (w2 * 32 + lr) * 32 + lgx8;

  for (int it = 0; it < 4; ++it) {
    __syncthreads();   // vmcnt drain == stage(it) landed
    f16x8 fah[2], fal[2], fbh[2], fbl[2];
    #pragma unroll
    for (int m = 0; m < 2; ++m) {
      fah[m] = *(const f16x8*)&Ah[offA0 + m * 512];
      fal[m] = *(const f16x8*)&Al[offA0 + m * 512];
    }
    #pragma unroll
    for (int n = 0; n < 2; ++n) {
      fbh[n] = *(const f16x8*)&Bh[offB0 + n * 512];
      fbl[n] = *(const f16x8*)&Bl[offB0 + n * 512];
    }
    __syncthreads();   // reads landed -> buffer free
    if (it < 3) STAGE((it + 1) * 32);   // flies under MFMAs
    #pragma unroll
    for (int m = 0; m < 2; ++m)
      #pragma unroll
      for (int n = 0; n < 2; ++n) {
        acc[m][n] = __builtin_amdgcn_mfma_f32_16x16x32_f16(fah[m], fbh[n], acc[m][n], 0, 0, 0);
        acc[m][n] = __builtin_amdgcn_mfma_f32_16x16x32_f16(fah[m], fbl[n], acc[m][n], 0, 0, 0);
        acc[m][n] = __builtin_amdgcn_mfma_f32_16x16x32_f16(fal[m], fbh[n], acc[m][n], 0, 0, 0);
      }
  }
#undef STAGE

  // ---- epilogue ----
  // corr-col n1 = bn1 + w1*32 + m*16 + lg*4 + q
  // corr-row n2 = bn2 + w2*32 + n*16 + lr
  float s2r[2];
  #pragma unroll
  for (int n = 0; n < 2; ++n) s2r[n] = s2s[w2 * 32 + n * 16 + lr];
  float s1r[2][4];
  #pragma unroll
  for (int m = 0; m < 2; ++m)
    #pragma unroll
    for (int q = 0; q < 4; ++q) s1r[m][q] = s1s[w1 * 32 + m * 16 + lg * 4 + q];

  float v21[2]; int i21[2];   // per n-row: min over this thread's 8 cols
  #pragma unroll
  for (int n = 0; n < 2; ++n) { v21[n] = 3.4e38f; i21[n] = 0; }

  float* cbp = corr + (size_t)b * NN * NN;
  #pragma unroll
  for (int m = 0; m < 2; ++m) {
    const int n1b = bn1 + w1 * 32 + m * 16 + lg * 4;
    float v12[4]; int i12[4];   // per q-col: min over this thread's 2 rows
    #pragma unroll
    for (int q = 0; q < 4; ++q) { v12[q] = 3.4e38f; i12[q] = 0; }
    #pragma unroll
    for (int n = 0; n < 2; ++n) {
      const int n2g = bn2 + w2 * 32 + n * 16 + lr;
      f32x4 dv;
      float sqc[4];
      #pragma unroll
      for (int q = 0; q < 4; ++q) {
        const float sv = fmaxf(fmaf(-2.0f, acc[m][n][q], s1r[m][q] + s2r[n]), 0.0f);
        sqc[q] = sv;
        dv[q] = fast_sqrt(sv);
      }
      __builtin_nontemporal_store(dv, (f32x4*)(cbp + (size_t)n2g * NN + n1b));
      #pragma unroll
      for (int q = 0; q < 4; ++q) {
        // n1 ascends with (m,q); n2 ascends with n: strict < = first-index
        if (sqc[q] < v21[n]) { v21[n] = sqc[q]; i21[n] = n1b + q; }
        if (sqc[q] < v12[q]) { v12[q] = sqc[q]; i12[q] = n2g; }
      }
    }
    // reduce v12 over the 16 lr-lanes; lanes lg=0..3 hold distinct col groups
    #pragma unroll
    for (int q = 0; q < 4; ++q) {
      float v = v12[q]; int idx = i12[q];
      #pragma unroll
      for (int mask = 1; mask < 16; mask <<= 1) {
        float ov = __shfl_xor(v, mask);
        int oi = __shfl_xor(idx, mask);
        if (ov < v || (ov == v && oi < idx)) { v = ov; idx = oi; }
      }
      if (lr == 0) {
        const size_t o = ((size_t)b * NN + n1b + q) * 128 + (sby * 2 + w2);
        p12[o] = f32x2{v, __int_as_float(idx)};
      }
    }
  }
  // reduce v21 over the 4 lg-lanes; lanes lr=0..15 hold distinct rows
  #pragma unroll
  for (int n = 0; n < 2; ++n) {
    float v = v21[n]; int idx = i21[n];
    #pragma unroll
    for (int mask = 16; mask < 64; mask <<= 1) {
      float ov = __shfl_xor(v, mask);
      int oi = __shfl_xor(idx, mask);
      if (ov < v || (ov == v && oi < idx)) { v = ov; idx = oi; }
    }
    if (lg == 0) {
      const int rowg = bn2 + w2 * 32 + n * 16 + lr;
      const size_t o = ((size_t)b * NN + rowg) * 128 + (sbx * 2 + w1);
      p21[o] = f32x2{v, __int_as_float(idx)};
    }
  }
}

// ---- final argmin: 128 f32x2 partials per output row, one wave each -----
__global__ __launch_bounds__(256) void argmin_reduce_kernel(
    const f32x2* __restrict__ p21, const f32x2* __restrict__ p12,
    float* __restrict__ out_i12, float* __restrict__ out_i21)
{
  int gtid = blockIdx.x * blockDim.x + threadIdx.x;
  int gwave = gtid >> 6;
  int lane = gtid & 63;
  const f32x2* pv; float* dst; int r;
  if (gwave < BB * NN) { r = gwave; pv = p21; dst = out_i21; }
  else { r = gwave - BB * NN; pv = p12; dst = out_i12; }
  f32x2 e1 = pv[(size_t)r * 128 + lane];
  f32x2 e2 = pv[(size_t)r * 128 + 64 + lane];
  float v = e1[0]; int idx = __float_as_int(e1[1]);
  {
    float v2 = e2[0]; int i2 = __float_as_int(e2[1]);
    if (v2 < v || (v2 == v && i2 < idx)) { v = v2; idx = i2; }
  }
  #pragma unroll
  for (int mask = 1; mask < 64; mask <<= 1) {
    float ov = __shfl_xor(v, mask);
    int oi = __shfl_xor(idx, mask);
    if (ov < v || (ov == v && oi < idx)) { v = ov; idx = oi; }
  }
  if (lane == 0) dst[r] = (float)idx;
}

extern "C" void kernel_launch(void* const* d_in, const int* in_sizes, int n_in,
                              void* d_out, int out_size, void* d_ws, size_t ws_size,
                              hipStream_t stream) {
  (void)in_sizes; (void)n_in; (void)out_size; (void)ws_size;
  const float* x1 = (const float*)d_in[0];
  const float* x2 = (const float*)d_in[1];
  float* out = (float*)d_out;
  char* ws = (char*)d_ws;
  const size_t nd = (size_t)BB * NN * DD;
  const size_t bn = (size_t)BB * NN;

  f16* x1h = (f16*)(ws + 0 * nd * 2);
  f16* x1l = (f16*)(ws + 1 * nd * 2);
  f16* x2h = (f16*)(ws + 2 * nd * 2);
  f16* x2l = (f16*)(ws + 3 * nd * 2);
  float* sq1 = (float*)(ws + 4 * nd * 2);
  float* sq2 = (float*)(ws + 4 * nd * 2 + bn * 4);
  f32x2* p21 = (f32x2*)(ws + 4 * nd * 2 + 2 * bn * 4);                 // 16.8 MB
  f32x2* p12 = (f32x2*)(ws + 4 * nd * 2 + 2 * bn * 4 + bn * 128 * 8); // 16.8 MB

  hipLaunchKernelGGL(prep_kernel, dim3(1024), dim3(256), 0, stream,
                     x1, x2, x1h, x1l, x2h, x2l, sq1, sq2, out);

  float* corr = out + 2 * nd;
  // grid: 64 x 64 tiles x 4 batches, 256-thread blocks, 5 blocks/CU
  hipLaunchKernelGGL(cdist_kernel, dim3(64, 64, 4), dim3(256), 0, stream,
                     x1h, x1l, x2h, x2l, sq1, sq2, corr, p21, p12);

  float* out_i12 = out + 2 * nd + bn * (size_t)NN;
  float* out_i21 = out_i12 + bn;
  hipLaunchKernelGGL(argmin_reduce_kernel, dim3(8192), dim3(256), 0, stream,
                     p21, p12, out_i12, out_i21);
}